// Round 3
// baseline (168.498 us; speedup 1.0000x reference)
//
#include <hip/hip_runtime.h>

#define NSAMP 128
#define VD 128   // voxel grid is 128^3 (fixed by problem instance)

__global__ __launch_bounds__(256)
void VoxelRenderer_kernel(const float* __restrict__ vol,   // [B,128,128,128,4]
                          const float* __restrict__ pose,  // [B,4,4]
                          const float* __restrict__ Kmat,  // [B,3,3]
                          const float* __restrict__ bmin,  // [B,3]
                          const float* __restrict__ bmax,  // [B,3]
                          const int* __restrict__ dH,
                          const int* __restrict__ dW,
                          float* __restrict__ out,         // [B,3,H,W]
                          int total)                       // B*H*W
{
    int tid = blockIdx.x * blockDim.x + threadIdx.x;
    if (tid >= total) return;
    const int H = dH[0], W = dW[0];
    const int N = H * W;
    const int b = tid / N;
    const int pix = tid - b * N;
    const int i = pix / W;
    const int j = pix - i * W;

    // ---- camera / ray setup ----
    const float* P  = pose + b * 16;
    const float* Kb = Kmat + b * 9;
    const float fx = Kb[0], cx = Kb[2], fy = Kb[4], cy = Kb[5];

    const float dcx = ((float)j - cx) / fx;
    const float dcy = -((float)i - cy) / fy;
    const float dcz = -1.0f;

    float dx = P[0]*dcx + P[1]*dcy + P[2]*dcz;
    float dy = P[4]*dcx + P[5]*dcy + P[6]*dcz;
    float dz = P[8]*dcx + P[9]*dcy + P[10]*dcz;
    float nrm = sqrtf(dx*dx + dy*dy + dz*dz);
    nrm = fmaxf(nrm, 1e-12f);
    dx /= nrm; dy /= nrm; dz /= nrm;

    const float ox = P[3], oy = P[7], oz = P[11];

    const float bx0 = bmin[b*3+0], by0 = bmin[b*3+1], bz0 = bmin[b*3+2];
    const float bx1 = bmax[b*3+0], by1 = bmax[b*3+1], bz1 = bmax[b*3+2];

    // ---- ray/box intersection (exact reference arithmetic) ----
    const float ivx = 1.0f / (dx + 1e-10f);
    const float ivy = 1.0f / (dy + 1e-10f);
    const float ivz = 1.0f / (dz + 1e-10f);

    float ta, tb;
    ta = (bx0 - ox) * ivx; tb = (bx1 - ox) * ivx;
    const float t1x = fminf(ta, tb), t2x = fmaxf(ta, tb);
    ta = (by0 - oy) * ivy; tb = (by1 - oy) * ivy;
    const float t1y = fminf(ta, tb), t2y = fmaxf(ta, tb);
    ta = (bz0 - oz) * ivz; tb = (bz1 - oz) * ivz;
    const float t1z = fminf(ta, tb), t2z = fmaxf(ta, tb);

    const float near = fmaxf(fmaxf(t1x, fmaxf(t1y, t1z)), 0.1f);
    const float far  = fmaxf(fminf(t2x, fminf(t2y, t2z)), near + 0.1f);

    // ---- voxel-space affine coords: v(t) = a + b*t  (align_corners=True) ----
    // x_vox = (px - bmin)/scale * 127
    const float sx = (bx1 - bx0) + 1e-10f;
    const float sy = (by1 - by0) + 1e-10f;
    const float sz = (bz1 - bz0) + 1e-10f;
    const float C = (float)(VD - 1);
    const float axv = (ox - bx0) / sx * C, bxv = dx / sx * C;
    const float ayv = (oy - by0) / sy * C, byv = dy / sy * C;
    const float azv = (oz - bz0) / sz * C, bzv = dz / sz * C;

    const float dt = (far - near) * (1.0f / (float)(NSAMP - 1));

    const float* __restrict__ V = vol + (size_t)b * VD * VD * VD * 4;

    float T = 1.0f;
    float rr = 0.0f, gg = 0.0f, bb = 0.0f, aw = 0.0f;

    for (int k = 0; k < NSAMP; ++k) {
        const float t = near + dt * (float)k;
        const float xf = axv + bxv * t;
        const float yf = ayv + byv * t;
        const float zf = azv + bzv * t;

        const float x0f = floorf(xf), y0f = floorf(yf), z0f = floorf(zf);
        const float xd = xf - x0f, yd = yf - y0f, zd = zf - z0f;
        const int x0 = (int)x0f, y0 = (int)y0f, z0 = (int)z0f;

        float sr = 0.0f, sg = 0.0f, sb = 0.0f, ss = 0.0f;

        #pragma unroll
        for (int cz = 0; cz < 2; ++cz) {
            const int zi = z0 + cz;
            const bool vz = (zi >= 0) & (zi < VD);
            const int zc = min(max(zi, 0), VD - 1);
            const float wz = cz ? zd : (1.0f - zd);
            #pragma unroll
            for (int cy = 0; cy < 2; ++cy) {
                const int yi = y0 + cy;
                const bool vy = (yi >= 0) & (yi < VD);
                const int yc = min(max(yi, 0), VD - 1);
                const float wy = cy ? yd : (1.0f - yd);
                #pragma unroll
                for (int cxd = 0; cxd < 2; ++cxd) {
                    const int xi = x0 + cxd;
                    const bool vx = (xi >= 0) & (xi < VD);
                    const int xc = min(max(xi, 0), VD - 1);
                    const float wxw = cxd ? xd : (1.0f - xd);
                    const float w = wz * wy * wxw * ((vz & vy & vx) ? 1.0f : 0.0f);
                    const float4 v = *reinterpret_cast<const float4*>(
                        V + (((size_t)(yc * VD + xc)) * VD + (size_t)zc) * 4);
                    sr += w * v.x;
                    sg += w * v.y;
                    sb += w * v.z;
                    ss += w * v.w;
                }
            }
        }

        const float sigma = fmaxf(ss, 0.0f);
        const float dist = (k == NSAMP - 1) ? 1e10f : dt;
        const float alpha = 1.0f - __expf(-sigma * dist);
        const float wgt = alpha * T;
        rr += wgt * sr;
        gg += wgt * sg;
        bb += wgt * sb;
        aw += wgt;
        T *= (1.0f - alpha + 1e-10f);
    }

    const float bg = 1.0f - aw;
    out[((size_t)(b * 3 + 0) * H + i) * W + j] = rr + bg;
    out[((size_t)(b * 3 + 1) * H + i) * W + j] = gg + bg;
    out[((size_t)(b * 3 + 2) * H + i) * W + j] = bb + bg;
}

extern "C" void kernel_launch(void* const* d_in, const int* in_sizes, int n_in,
                              void* d_out, int out_size, void* d_ws, size_t ws_size,
                              hipStream_t stream) {
    const float* rgbsigma = (const float*)d_in[0];
    const float* pose     = (const float*)d_in[1];
    const float* Kmat     = (const float*)d_in[2];
    const float* bmin     = (const float*)d_in[3];
    const float* bmax     = (const float*)d_in[4];
    const int*   dH       = (const int*)d_in[5];
    const int*   dW       = (const int*)d_in[6];
    float* out = (float*)d_out;

    const int total = out_size / 3;  // B*H*W rays
    const int block = 256;
    const int grid = (total + block - 1) / block;
    VoxelRenderer_kernel<<<grid, block, 0, stream>>>(
        rgbsigma, pose, Kmat, bmin, bmax, dH, dW, out, total);
}